// Round 1
// baseline (7253.744 us; speedup 1.0000x reference)
//
#include <hip/hip_runtime.h>
#include <hip/hip_bf16.h>
#include <math.h>

// Problem constants (match reference setup_inputs)
#define N_NODES   50000
#define N_EDGES   800000
#define IN_DIM    3703
#define HIDDEN    500
#define N_CLASSES 6

// ---------------- GEMM: C[M,N] = A[M,K] @ B[K,N], fp32, row-major ----------------
#define BM 64
#define BN 64
#define BK 16

__global__ __launch_bounds__(256) void gemm_f32(const float* __restrict__ A,
                                                const float* __restrict__ B,
                                                float* __restrict__ C,
                                                int M, int K, int N) {
    __shared__ float As[BK][BM + 4];  // As[k][m], pad keeps 16B alignment for b128 reads
    __shared__ float Bs[BK][BN];      // Bs[k][n]

    int tid = threadIdx.x;
    int tx = tid & 15;   // n-quad index
    int ty = tid >> 4;   // m-quad index
    int m0 = blockIdx.y * BM;
    int n0 = blockIdx.x * BN;

    float acc[4][4] = {};

    // A loader: thread -> row ar (0..63), k-cols ac..ac+3
    int ar = tid >> 2;
    int ac = (tid & 3) * 4;
    // B loader: thread -> col bc (0..63), rows br, br+4, br+8, br+12
    int bc = tid & 63;
    int br = tid >> 6;

    for (int k0 = 0; k0 < K; k0 += BK) {
#pragma unroll
        for (int j = 0; j < 4; j++) {
            int m = m0 + ar;
            int k = k0 + ac + j;
            As[ac + j][ar] = (m < M && k < K) ? A[(size_t)m * K + k] : 0.f;
        }
#pragma unroll
        for (int j = 0; j < 4; j++) {
            int k = k0 + br + j * 4;
            int n = n0 + bc;
            Bs[br + j * 4][bc] = (k < K && n < N) ? B[(size_t)k * N + n] : 0.f;
        }
        __syncthreads();
#pragma unroll
        for (int k = 0; k < BK; k++) {
            float a[4], b[4];
#pragma unroll
            for (int i = 0; i < 4; i++) a[i] = As[k][ty * 4 + i];
#pragma unroll
            for (int j = 0; j < 4; j++) b[j] = Bs[k][tx * 4 + j];
#pragma unroll
            for (int i = 0; i < 4; i++)
#pragma unroll
                for (int j = 0; j < 4; j++)
                    acc[i][j] += a[i] * b[j];
        }
        __syncthreads();
    }

#pragma unroll
    for (int i = 0; i < 4; i++) {
        int m = m0 + ty * 4 + i;
        if (m >= M) continue;
#pragma unroll
        for (int j = 0; j < 4; j++) {
            int n = n0 + tx * 4 + j;
            if (n < N) C[(size_t)m * N + n] = acc[i][j];
        }
    }
}

// ---------------- CSR build ----------------
__global__ void count_deg(const int* __restrict__ dst, int* __restrict__ deg, int E) {
    int i = blockIdx.x * blockDim.x + threadIdx.x;
    if (i < E) atomicAdd(&deg[dst[i]], 1);
}

// exclusive scan of 256-chunks; bsum gets chunk totals (pass nullptr to skip)
__global__ void scan_block(const int* __restrict__ in, int* __restrict__ out,
                           int* __restrict__ bsum, int n) {
    __shared__ int s[256];
    int i = blockIdx.x * 256 + threadIdx.x;
    int v = (i < n) ? in[i] : 0;
    s[threadIdx.x] = v;
    __syncthreads();
    for (int off = 1; off < 256; off <<= 1) {
        int t = (threadIdx.x >= (unsigned)off) ? s[threadIdx.x - off] : 0;
        __syncthreads();
        s[threadIdx.x] += t;
        __syncthreads();
    }
    if (i < n) out[i] = s[threadIdx.x] - v;  // exclusive
    if (bsum && threadIdx.x == 255) bsum[blockIdx.x] = s[255];
}

__global__ void scan_add(int* __restrict__ out, const int* __restrict__ bsum, int n, int E) {
    int i = blockIdx.x * 256 + threadIdx.x;
    if (i < n) out[i] += bsum[blockIdx.x];
    if (i == 0) out[n] = E;  // total
}

__global__ void scatter_edges(const int* __restrict__ dst, const int* __restrict__ offs,
                              int* __restrict__ cursor, int* __restrict__ eid, int E) {
    int e = blockIdx.x * blockDim.x + threadIdx.x;
    if (e < E) {
        int d = dst[e];
        int p = atomicAdd(&cursor[d], 1);
        eid[offs[d] + p] = e;
    }
}

// ---------------- aggregation: out[n] = relu?( sum_e w*P[src] + bias ) ----------------
__global__ __launch_bounds__(256) void aggregate_k(const float* __restrict__ P,
                                                   const int* __restrict__ offs,
                                                   const int* __restrict__ eid,
                                                   const int* __restrict__ src,
                                                   const float* __restrict__ ew,
                                                   const float* __restrict__ bias,
                                                   float* __restrict__ out,
                                                   int do_relu) {
    int n = blockIdx.x;
    int tid = threadIdx.x;
    int beg = offs[n], end = offs[n + 1];
    float a0 = 0.f, a1 = 0.f;
    for (int i = beg; i < end; i++) {
        int e = eid[i];
        int s = src[e];
        float w = ew[e];
        const float* row = P + (size_t)s * HIDDEN;
        a0 += w * row[tid];
        if (tid + 256 < HIDDEN) a1 += w * row[tid + 256];
    }
    float v0 = a0 + bias[tid];
    if (do_relu) v0 = fmaxf(v0, 0.f);
    out[(size_t)n * HIDDEN + tid] = v0;
    if (tid + 256 < HIDDEN) {
        float v1 = a1 + bias[tid + 256];
        if (do_relu) v1 = fmaxf(v1, 0.f);
        out[(size_t)n * HIDDEN + tid + 256] = v1;
    }
}

// ---------------- layer 3 ----------------
__global__ void logits_k(const float* __restrict__ H, const float* __restrict__ W3,
                         float* __restrict__ L) {
    int t = blockIdx.x * blockDim.x + threadIdx.x;
    if (t >= N_NODES * N_CLASSES) return;
    int n = t / N_CLASSES, c = t % N_CLASSES;
    const float* row = H + (size_t)n * HIDDEN;
    float acc = 0.f;
    for (int k = 0; k < HIDDEN; k++) acc += row[k] * W3[k * N_CLASSES + c];
    L[t] = acc;
}

__global__ void agg_logits(const float* __restrict__ L, const int* __restrict__ src,
                           const int* __restrict__ dst, const float* __restrict__ ew,
                           float* __restrict__ aggL, int E) {
    int e = blockIdx.x * blockDim.x + threadIdx.x;
    if (e >= E) return;
    int s = src[e], d = dst[e];
    float w = ew[e];
#pragma unroll
    for (int c = 0; c < N_CLASSES; c++)
        atomicAdd(&aggL[(size_t)d * N_CLASSES + c], w * L[(size_t)s * N_CLASSES + c]);
}

__global__ void log_softmax_k(const float* __restrict__ aggL, const float* __restrict__ b3,
                              float* __restrict__ out) {
    int n = blockIdx.x * blockDim.x + threadIdx.x;
    if (n >= N_NODES) return;
    float v[N_CLASSES];
    float m = -1e30f;
#pragma unroll
    for (int c = 0; c < N_CLASSES; c++) {
        v[c] = aggL[(size_t)n * N_CLASSES + c] + b3[c];
        m = fmaxf(m, v[c]);
    }
    float s = 0.f;
#pragma unroll
    for (int c = 0; c < N_CLASSES; c++) s += expf(v[c] - m);
    float ls = logf(s) + m;
#pragma unroll
    for (int c = 0; c < N_CLASSES; c++) out[(size_t)n * N_CLASSES + c] = v[c] - ls;
}

// ---------------- launch ----------------
extern "C" void kernel_launch(void* const* d_in, const int* in_sizes, int n_in,
                              void* d_out, int out_size, void* d_ws, size_t ws_size,
                              hipStream_t stream) {
    const float* x   = (const float*)d_in[0];
    const float* w1  = (const float*)d_in[1];
    const float* b1  = (const float*)d_in[2];
    const float* w2  = (const float*)d_in[3];
    const float* b2  = (const float*)d_in[4];
    const float* w3  = (const float*)d_in[5];
    const float* b3  = (const float*)d_in[6];
    const float* ew  = (const float*)d_in[7];
    const int* esrc  = (const int*)d_in[8];
    const int* edst  = (const int*)d_in[9];
    float* out = (float*)d_out;

    // workspace layout
    char* ws = (char*)d_ws;
    size_t off = 0;
    auto alloc = [&](size_t bytes) {
        void* p = ws + off;
        off += (bytes + 255) & ~(size_t)255;
        return p;
    };
    float* bufA   = (float*)alloc((size_t)N_NODES * HIDDEN * 4);     // pre-agg
    float* bufB   = (float*)alloc((size_t)N_NODES * HIDDEN * 4);     // post-agg
    float* L      = (float*)alloc((size_t)N_NODES * N_CLASSES * 4);
    float* aggL   = (float*)alloc((size_t)N_NODES * N_CLASSES * 4);
    int* deg      = (int*)alloc((size_t)N_NODES * 4);
    int* offs     = (int*)alloc((size_t)(N_NODES + 1) * 4);
    int* cursor   = (int*)alloc((size_t)N_NODES * 4);
    int* bsum     = (int*)alloc(256 * 4);
    int* eid      = (int*)alloc((size_t)N_EDGES * 4);
    (void)ws_size; (void)n_in; (void)in_sizes; (void)out_size;

    const int E = N_EDGES;
    const int nScanBlocks = (N_NODES + 255) / 256;  // 196

    // zero-init accumulators (ws is poisoned 0xAA before every launch)
    hipMemsetAsync(deg, 0, (size_t)N_NODES * 4, stream);
    hipMemsetAsync(cursor, 0, (size_t)N_NODES * 4, stream);
    hipMemsetAsync(aggL, 0, (size_t)N_NODES * N_CLASSES * 4, stream);

    // CSR build
    count_deg<<<(E + 255) / 256, 256, 0, stream>>>(edst, deg, E);
    scan_block<<<nScanBlocks, 256, 0, stream>>>(deg, offs, bsum, N_NODES);
    scan_block<<<1, 256, 0, stream>>>(bsum, bsum, nullptr, nScanBlocks);
    scan_add<<<nScanBlocks, 256, 0, stream>>>(offs, bsum, N_NODES, E);
    scatter_edges<<<(E + 255) / 256, 256, 0, stream>>>(edst, offs, cursor, eid, E);

    // layer 1
    {
        dim3 grid((HIDDEN + BN - 1) / BN, (N_NODES + BM - 1) / BM);
        gemm_f32<<<grid, 256, 0, stream>>>(x, w1, bufA, N_NODES, IN_DIM, HIDDEN);
    }
    aggregate_k<<<N_NODES, 256, 0, stream>>>(bufA, offs, eid, esrc, ew, b1, bufB, 1);

    // layer 2
    {
        dim3 grid((HIDDEN + BN - 1) / BN, (N_NODES + BM - 1) / BM);
        gemm_f32<<<grid, 256, 0, stream>>>(bufB, w2, bufA, N_NODES, HIDDEN, HIDDEN);
    }
    aggregate_k<<<N_NODES, 256, 0, stream>>>(bufA, offs, eid, esrc, ew, b2, bufB, 1);

    // layer 3
    logits_k<<<(N_NODES * N_CLASSES + 255) / 256, 256, 0, stream>>>(bufB, w3, L);
    agg_logits<<<(E + 255) / 256, 256, 0, stream>>>(L, esrc, edst, ew, aggL, E);
    log_softmax_k<<<(N_NODES + 255) / 256, 256, 0, stream>>>(aggL, b3, out);
}